// Round 10
// baseline (3009.763 us; speedup 1.0000x reference)
//
#include <hip/hip_runtime.h>

typedef __attribute__((ext_vector_type(8))) short short8;
typedef __attribute__((ext_vector_type(4))) float f32x4;
typedef unsigned short ushort_t;

#define T_DIM 64
#define N_DIM 4096
#define DL 300
#define DA 74
#define DV 35
#define DTOT 409
#define ZD 256
#define FD 128
#define KP1_L 320
#define KP1_A 96
#define KP1_V 64
#define KC_L ((KP1_L + 256) / 32)   // 18
#define KC_A ((KP1_A + 256) / 32)   // 11
#define KC_V ((KP1_V + 256) / 32)   // 10

__device__ __forceinline__ ushort_t f2bf(float v) {
    unsigned u = __float_as_uint(v);
    u += 0x7fffu + ((u >> 16) & 1u);
    return (ushort_t)(u >> 16);
}

__device__ __forceinline__ float fastrcp(float x) {
#if __has_builtin(__builtin_amdgcn_rcpf)
    return __builtin_amdgcn_rcpf(x);
#else
    return 1.f / x;
#endif
}

// async global->LDS, 16B per lane
__device__ __forceinline__ void async_lds16(const ushort_t* g, ushort_t* l) {
    __builtin_amdgcn_global_load_lds(
        (const __attribute__((address_space(1))) unsigned int*)g,
        (__attribute__((address_space(3))) unsigned int*)l, 16, 0, 0);
}

// ---------------------------------------------------------------------------
// prep: one pass over x -> (1) the three fp32 output slices, (2) bf16
// A-fragment buffers xf[m] : [t][nb][kc][lane][8].
// ---------------------------------------------------------------------------
struct PrepP {
    const float* x;
    float* ol;
    float* oa;
    float* ov;
    ushort_t* xf[3];
};
__global__ __launch_bounds__(256) void prep_kernel(PrepP p) {
    __shared__ float xrow[16][420];
    const int bid = blockIdx.x;
    const int t = bid >> 8, nb = bid & 255;
    const int tid = threadIdx.x;
    const size_t rowbase = (size_t)t * N_DIM + (size_t)nb * 16;

    const float* __restrict__ src = p.x + rowbase * DTOT;
    for (int e = tid; e < 16 * DTOT; e += 256) {
        int r = e / DTOT, d = e - r * DTOT;
        xrow[r][d] = src[e];
    }
    __syncthreads();

    {
        float* __restrict__ dl = p.ol + rowbase * DL;
        for (int e = tid; e < 16 * DL; e += 256) { int r = e / DL, d = e - r * DL; dl[e] = xrow[r][d]; }
        float* __restrict__ da = p.oa + rowbase * DA;
        for (int e = tid; e < 16 * DA; e += 256) { int r = e / DA, d = e - r * DA; da[e] = xrow[r][300 + d]; }
        float* __restrict__ dv = p.ov + rowbase * DV;
        for (int e = tid; e < 16 * DV; e += 256) { int r = e / DV, d = e - r * DV; dv[e] = xrow[r][374 + d]; }
    }

    const unsigned tnb = (unsigned)t * 256u + (unsigned)nb;
    for (int q = tid; q < 960; q += 256) {
        int m, kc, l, xkc, col0, dcap;
        if (q < 640)      { m = 0; kc = q >> 6;          l = q & 63; xkc = 10; col0 = 0;   dcap = DL; }
        else if (q < 832) { int qq = q - 640; m = 1; kc = qq >> 6; l = qq & 63; xkc = 3; col0 = 300; dcap = DA; }
        else              { int qq = q - 832; m = 2; kc = qq >> 6; l = qq & 63; xkc = 2; col0 = 374; dcap = DV; }
        int n16 = l & 15;
        int kb = kc * 32 + (l >> 4) * 8;
        ushort_t tmp[8];
#pragma unroll
        for (int j = 0; j < 8; ++j) {
            int k = kb + j;
            tmp[j] = (k < dcap) ? f2bf(xrow[n16][col0 + k]) : (ushort_t)0;
        }
        ushort_t* dst = p.xf[m] + (((size_t)tnb * xkc + kc) * 64 + l) * 8;
        *reinterpret_cast<short8*>(dst) = *reinterpret_cast<short8*>(tmp);
    }
}

// ---------------------------------------------------------------------------
// Weight conversion into B-fragment stream order:
// chunk id = ((zs*4 + g)*KC + kc), chunk = [lane 64][8] bf16.
// ---------------------------------------------------------------------------
struct WConvP {
    const float* Wih[3];
    const float* Whh[3];
    ushort_t* wf[3];
};
__global__ __launch_bounds__(256) void wconv_kernel(WConvP p) {
    const unsigned CL = 16u * 4 * KC_L * 64;
    const unsigned CA = 16u * 4 * KC_A * 64;
    const unsigned CV = 16u * 4 * KC_V * 64;
    unsigned e = blockIdx.x * 256u + threadIdx.x;
    int m, kcm, d, kp1;
    unsigned rel;
    if (e < CL)                { m = 0; rel = e;           kcm = KC_L; d = DL; kp1 = KP1_L; }
    else if (e < CL + CA)      { m = 1; rel = e - CL;      kcm = KC_A; d = DA; kp1 = KP1_A; }
    else if (e < CL + CA + CV) { m = 2; rel = e - CL - CA; kcm = KC_V; d = DV; kp1 = KP1_V; }
    else return;
    unsigned lane = rel & 63u;
    unsigned rest = rel >> 6;
    unsigned kc = rest % (unsigned)kcm;
    unsigned zg = rest / (unsigned)kcm;
    unsigned g = zg & 3u, zs = zg >> 2;
    unsigned row = g * 256u + zs * 16u + (lane & 15u);
    unsigned kb = kc * 32u + (lane >> 4) * 8u;
    const float* __restrict__ Wih = p.Wih[m];
    const float* __restrict__ Whh = p.Whh[m];
    ushort_t tmp[8];
#pragma unroll
    for (int j = 0; j < 8; ++j) {
        int k = (int)kb + j;
        float v = 0.f;
        if (k < d) v = Wih[(size_t)row * d + k];
        else if (k >= kp1) v = Whh[(size_t)row * 256u + (k - kp1)];
        tmp[j] = f2bf(v);
    }
    *reinterpret_cast<short8*>(p.wf[m] + (size_t)rel * 8) = *reinterpret_cast<short8*>(tmp);
}

// ---------------------------------------------------------------------------
// Independent-chain LSTM v3:
//  - grid rebalanced: L = 128 blocks x 32 rows, A/V = 64 blocks x 64 rows
//    (256 blocks total, 1/CU, no idle CUs; per-wave MFMA nearly uniform)
//  - kc loop FULLY UNROLLED with PF-deep static-indexed b prefetch
//    (covers L2 latency; rule-#20-safe: all indices compile-time)
//  - x tiles async global_load_lds double-buffered (issued mid-step)
//  - h in LDS double buffer; c in registers
// ---------------------------------------------------------------------------
struct ChainP {
    const ushort_t* xf[3];
    const ushort_t* wf[3];
    const float* bih[3];
    const float* bhh[3];
    float* hf;   // [3][N][256] f32, written at t=63
};

template <int KP1, int RF>
__device__ __forceinline__ void chain_body(const ChainP& p, int m, int row0, ushort_t* sh) {
    constexpr int XKC = KP1 / 32;
    constexpr int KC = XKC + 8;
    constexpr int XCH = RF * XKC;           // x chunks per tile
    constexpr int XSZ = XCH * 512;          // ushorts per x buffer
    constexpr int HSZ = RF * 4096;          // ushorts per h buffer
    constexpr int PF = (RF == 2) ? 4 : 3;   // b prefetch depth
    const int tid = threadIdx.x;
    const int w = tid >> 6, lane = tid & 63, ln = lane & 15, lg = lane >> 4;
    const int nb0 = row0 >> 4;

    ushort_t* hb0 = sh;                     // 2 x HSZ
    ushort_t* xb0 = sh + 2 * HSZ;           // 2 x XSZ
    const ushort_t* __restrict__ xf = p.xf[m];
    const ushort_t* __restrict__ wf = p.wf[m];

    // zero h buffer 0
    for (int e = tid; e < RF * 2048; e += 512) ((unsigned*)hb0)[e] = 0u;

    // prologue: async-stage x tile for t=0 into buffer 0
    for (int q = w; q < XCH; q += 8) {
        int rf = q / XKC, kc = q - rf * XKC;
        const ushort_t* src = xf + (((size_t)0 * 256 + nb0 + rf) * XKC + kc) * 512 + lane * 8;
        async_lds16(src, xb0 + (size_t)q * 512);
    }

    float bb4[2][4];
#pragma unroll
    for (int pp = 0; pp < 2; ++pp) {
        int z = pp * 128 + w * 16 + ln;
        bb4[pp][0] = p.bih[m][z] + p.bhh[m][z];
        bb4[pp][1] = p.bih[m][256 + z] + p.bhh[m][256 + z];
        bb4[pp][2] = p.bih[m][512 + z] + p.bhh[m][512 + z];
        bb4[pp][3] = p.bih[m][768 + z] + p.bhh[m][768 + z];
    }
    float creg[2][RF][4] = {};
    asm volatile("s_waitcnt vmcnt(0)" ::: "memory");
    __syncthreads();

#pragma unroll 1
    for (int t = 0; t < T_DIM; ++t) {
        const ushort_t* __restrict__ xbc = xb0 + (size_t)(t & 1) * XSZ;
        const ushort_t* __restrict__ hbc = hb0 + (size_t)(t & 1) * HSZ;
        ushort_t* __restrict__ hbn = hb0 + (size_t)((t & 1) ^ 1) * HSZ;

#pragma unroll
        for (int pp = 0; pp < 2; ++pp) {
            const int zs = pp * 8 + w;
            const ushort_t* __restrict__ wfz = wf + (size_t)zs * 4 * KC * 512;
            f32x4 acc[RF][4] = {};
            short8 bbuf[PF][4];
#pragma unroll
            for (int i = 0; i < PF; ++i)
#pragma unroll
                for (int g = 0; g < 4; ++g)
                    bbuf[i][g] = *reinterpret_cast<const short8*>(
                        wfz + ((size_t)g * KC + i) * 512 + lane * 8);

#pragma unroll
            for (int kc = 0; kc < KC; ++kc) {
                short8 a[RF];
                if (kc < XKC) {
#pragma unroll
                    for (int rf = 0; rf < RF; ++rf)
                        a[rf] = *reinterpret_cast<const short8*>(
                            xbc + ((size_t)(rf * XKC + kc) * 64 + lane) * 8);
                } else {
#pragma unroll
                    for (int rf = 0; rf < RF; ++rf)
                        a[rf] = *reinterpret_cast<const short8*>(
                            hbc + ((size_t)(rf * 8 + (kc - XKC)) * 64 + lane) * 8);
                }
#pragma unroll
                for (int g = 0; g < 4; ++g)
#pragma unroll
                    for (int rf = 0; rf < RF; ++rf)
                        acc[rf][g] = __builtin_amdgcn_mfma_f32_16x16x32_bf16(
                            a[rf], bbuf[kc % PF][g], acc[rf][g], 0, 0, 0);
                if (kc + PF < KC) {
#pragma unroll
                    for (int g = 0; g < 4; ++g)
                        bbuf[kc % PF][g] = *reinterpret_cast<const short8*>(
                            wfz + ((size_t)g * KC + kc + PF) * 512 + lane * 8);
                }
            }

            // mid-step (after pass 0 issues): async-stage next step's x tile
            if (pp == 0 && t + 1 < T_DIM) {
                ushort_t* xbn = xb0 + (size_t)((t & 1) ^ 1) * XSZ;
                for (int q = w; q < XCH; q += 8) {
                    int rf = q / XKC, kc = q - rf * XKC;
                    const ushort_t* src =
                        xf + (((size_t)(t + 1) * 256 + nb0 + rf) * XKC + kc) * 512 + lane * 8;
                    async_lds16(src, xbn + (size_t)q * 512);
                }
            }

            // pointwise epilogue; h -> LDS next buffer (A-frag layout)
            const int z = pp * 128 + w * 16 + ln;
            const int kc2 = z >> 5;
            const int bofs = ((z >> 3) & 3) * 16;
            const int jj = z & 7;
#pragma unroll
            for (int rf = 0; rf < RF; ++rf) {
#pragma unroll
                for (int reg = 0; reg < 4; ++reg) {
                    float gi = acc[rf][0][reg] + bb4[pp][0];
                    float gf = acc[rf][1][reg] + bb4[pp][1];
                    float gg = acc[rf][2][reg] + bb4[pp][2];
                    float go = acc[rf][3][reg] + bb4[pp][3];
                    float i_ = fastrcp(1.f + __expf(-gi));
                    float f_ = fastrcp(1.f + __expf(-gf));
                    float g_ = 1.f - 2.f * fastrcp(1.f + __expf(2.f * gg));
                    float o_ = fastrcp(1.f + __expf(-go));
                    float cc = f_ * creg[pp][rf][reg] + i_ * g_;
                    creg[pp][rf][reg] = cc;
                    float hh = o_ * (1.f - 2.f * fastrcp(1.f + __expf(2.f * cc)));
                    hbn[((size_t)(rf * 8 + kc2) * 64 + (lg * 4 + reg + bofs)) * 8 + jj] = f2bf(hh);
                    if (t == T_DIM - 1) {
                        int nl = rf * 16 + lg * 4 + reg;
                        p.hf[(size_t)m * N_DIM * ZD + (size_t)(row0 + nl) * ZD + z] = hh;
                    }
                }
            }
        }

        // drain next-step x-tile loads, then step barrier
        asm volatile("s_waitcnt vmcnt(0)" ::: "memory");
        __syncthreads();
    }
}

__global__ __launch_bounds__(512, 1) void lstm_chain_kernel(ChainP p) {
    __shared__ ushort_t sh[45056];   // 90112 B (max: A = 64KB h + 24KB x)
    const int bid = blockIdx.x;
    const int r8 = bid & 7, idx = bid >> 3;
    if (idx < 16) {
        const int bm = idx * 8 + r8;          // 0..127
        chain_body<KP1_L, 2>(p, 0, bm * 32, sh);
    } else if (idx < 24) {
        const int bm = (idx - 16) * 8 + r8;   // 0..63
        chain_body<KP1_A, 4>(p, 1, bm * 64, sh);
    } else {
        const int bm = (idx - 24) * 8 + r8;   // 0..63
        chain_body<KP1_V, 4>(p, 2, bm * 64, sh);
    }
}

// ---------------------------------------------------------------------------
// fp32 tiled GEMM for the head layers
// ---------------------------------------------------------------------------
struct GemmP {
    const float* A1[3];
    const float* W1[3];
    const float* b1[3];
    float* C[3];
    int K1[3];
    int lda1;
    int ldc;
    int relu;
};

__device__ __forceinline__ void mac16(const float (&As)[16][64], const float (&Ws)[16][64],
                                      int tx, int ty, float (&acc)[4][4]) {
#pragma unroll
    for (int k = 0; k < 16; ++k) {
        float4 av = *reinterpret_cast<const float4*>(&As[k][ty * 4]);
        float4 bv = *reinterpret_cast<const float4*>(&Ws[k][tx * 4]);
        float a[4] = {av.x, av.y, av.z, av.w};
        float b[4] = {bv.x, bv.y, bv.z, bv.w};
#pragma unroll
        for (int i = 0; i < 4; ++i)
#pragma unroll
            for (int j = 0; j < 4; ++j)
                acc[i][j] = fmaf(a[i], b[j], acc[i][j]);
    }
}

__global__ __launch_bounds__(256) void gemm3_kernel(GemmP p) {
    const int m = blockIdx.z;
    const float* __restrict__ A1 = p.A1[m];
    const float* __restrict__ W1 = p.W1[m];
    const int K1 = p.K1[m];
    float* __restrict__ C = p.C[m];
    const int row0 = blockIdx.x * 64;
    const int col0 = blockIdx.y * 64;

    __shared__ __align__(16) float As[16][64];
    __shared__ __align__(16) float Ws[16][64];

    const int tid = threadIdx.x;
    const int tx = tid & 15, ty = tid >> 4;
    float acc[4][4] = {};

    for (int k0 = 0; k0 < K1; k0 += 16) {
#pragma unroll
        for (int i = 0; i < 4; ++i) {
            int e = tid * 4 + i;
            int rr = e >> 4, k = e & 15;
            int kk = k0 + k;
            As[k][rr] = (kk < K1) ? A1[(size_t)(row0 + rr) * p.lda1 + kk] : 0.f;
            Ws[k][rr] = (kk < K1) ? W1[(size_t)(col0 + rr) * K1 + kk] : 0.f;
        }
        __syncthreads();
        mac16(As, Ws, tx, ty, acc);
        __syncthreads();
    }

    const float* __restrict__ b1 = p.b1[m];
#pragma unroll
    for (int i = 0; i < 4; ++i) {
        int rr = row0 + ty * 4 + i;
        float v[4];
#pragma unroll
        for (int j = 0; j < 4; ++j) {
            int cc = col0 + tx * 4 + j;
            float tvl = acc[i][j] + b1[cc];
            if (p.relu) tvl = fmaxf(tvl, 0.f);
            v[j] = tvl;
        }
        float4 o = make_float4(v[0], v[1], v[2], v[3]);
        *reinterpret_cast<float4*>(&C[(size_t)rr * p.ldc + col0 + tx * 4]) = o;
    }
}

// ---------------------------------------------------------------------------
// y[n] = dot(fs[n,:384], Wy) + by
// ---------------------------------------------------------------------------
__global__ __launch_bounds__(256) void y_kernel(const float* __restrict__ fs,
                                                const float* __restrict__ Wy,
                                                const float* __restrict__ by,
                                                float* __restrict__ y) {
    unsigned wave = (blockIdx.x * 256u + threadIdx.x) >> 6;
    unsigned lane = threadIdx.x & 63u;
    if (wave >= N_DIM) return;
    const float* row = fs + (size_t)wave * 3 * FD;
    float s = 0.f;
    for (unsigned j = lane; j < 3 * FD; j += 64) s += row[j] * Wy[j];
#pragma unroll
    for (int off = 32; off; off >>= 1) s += __shfl_down(s, off);
    if (lane == 0) y[wave] = s + by[0];
}

extern "C" void kernel_launch(void* const* d_in, const int* in_sizes, int n_in,
                              void* d_out, int out_size, void* d_ws, size_t ws_size,
                              hipStream_t stream) {
    const float* x = (const float*)d_in[0];
    const float *W_ih[3], *W_hh[3], *b_ih[3], *b_hh[3], *Wfc[3], *bfc[3],
                *Wh1[3], *bh1[3], *Wh2[3], *bh2[3];
    for (int m = 0; m < 3; ++m) {
        const int b = 1 + m * 10;
        W_ih[m] = (const float*)d_in[b + 0];
        W_hh[m] = (const float*)d_in[b + 1];
        b_ih[m] = (const float*)d_in[b + 2];
        b_hh[m] = (const float*)d_in[b + 3];
        Wfc[m]  = (const float*)d_in[b + 4];
        bfc[m]  = (const float*)d_in[b + 5];
        Wh1[m]  = (const float*)d_in[b + 6];
        bh1[m]  = (const float*)d_in[b + 7];
        Wh2[m]  = (const float*)d_in[b + 8];
        bh2[m]  = (const float*)d_in[b + 9];
    }
    const float* Wy = (const float*)d_in[31];
    const float* by = (const float*)d_in[32];

    float* out   = (float*)d_out;
    float* out_l = out;
    float* out_a = out_l + (size_t)T_DIM * N_DIM * DL;
    float* out_v = out_a + (size_t)T_DIM * N_DIM * DA;
    float* out_y = out_v + (size_t)T_DIM * N_DIM * DV;

    const size_t NZ = (size_t)N_DIM * ZD;
    const size_t NF = (size_t)N_DIM * FD;
    const size_t WFL = (size_t)16 * 4 * KC_L * 512;
    const size_t WFA = (size_t)16 * 4 * KC_A * 512;
    const size_t WFV = (size_t)16 * 4 * KC_V * 512;

    // workspace layout
    char* wsb = (char*)d_ws;
    float* hf   = (float*)wsb;                              // 3NZ f32
    float* zbuf = hf + 3 * NZ;
    float* f1   = zbuf + 3 * NZ;
    float* fs   = f1 + 3 * NF;
    ushort_t* wf_l = (ushort_t*)(fs + 3 * NF);
    ushort_t* wf_a = wf_l + WFL;
    ushort_t* wf_v = wf_a + WFA;
    ushort_t* xf_l = wf_v + WFV;                            // T*N*320
    ushort_t* xf_a = xf_l + (size_t)T_DIM * N_DIM * KP1_L;  // T*N*96
    ushort_t* xf_v = xf_a + (size_t)T_DIM * N_DIM * KP1_A;  // T*N*64
    size_t need = (size_t)((char*)(xf_v + (size_t)T_DIM * N_DIM * KP1_V) - wsb);
    if (ws_size < need) return;

    // weight fragment conversion
    {
        WConvP p{};
        for (int m = 0; m < 3; ++m) { p.Wih[m] = W_ih[m]; p.Whh[m] = W_hh[m]; }
        p.wf[0] = wf_l; p.wf[1] = wf_a; p.wf[2] = wf_v;
        wconv_kernel<<<(16 * 4 * (KC_L + KC_A + KC_V) * 64) / 256, 256, 0, stream>>>(p);
    }

    // fused split + x fragment conversion
    {
        PrepP p{};
        p.x = x;
        p.ol = out_l; p.oa = out_a; p.ov = out_v;
        p.xf[0] = xf_l; p.xf[1] = xf_a; p.xf[2] = xf_v;
        prep_kernel<<<T_DIM * 256, 256, 0, stream>>>(p);
    }

    // independent-chain LSTM (256 blocks, 1/CU)
    {
        ChainP cp{};
        cp.xf[0] = xf_l; cp.xf[1] = xf_a; cp.xf[2] = xf_v;
        cp.wf[0] = wf_l; cp.wf[1] = wf_a; cp.wf[2] = wf_v;
        for (int m = 0; m < 3; ++m) { cp.bih[m] = b_ih[m]; cp.bhh[m] = b_hh[m]; }
        cp.hf = hf;
        lstm_chain_kernel<<<256, 512, 0, stream>>>(cp);
    }

    // z = h @ Wfc^T + bfc
    {
        GemmP p{};
        for (int m = 0; m < 3; ++m) {
            p.A1[m] = hf + m * NZ; p.W1[m] = Wfc[m]; p.K1[m] = ZD;
            p.b1[m] = bfc[m];      p.C[m] = zbuf + m * NZ;
        }
        p.lda1 = ZD; p.ldc = ZD; p.relu = 0;
        gemm3_kernel<<<dim3(N_DIM / 64, ZD / 64, 3), 256, 0, stream>>>(p);
    }
    // f1 = relu(z @ Wh1^T + bh1)
    {
        GemmP p{};
        for (int m = 0; m < 3; ++m) {
            p.A1[m] = zbuf + m * NZ; p.W1[m] = Wh1[m]; p.K1[m] = ZD;
            p.b1[m] = bh1[m];        p.C[m] = f1 + m * NF;
        }
        p.lda1 = ZD; p.ldc = FD; p.relu = 1;
        gemm3_kernel<<<dim3(N_DIM / 64, FD / 64, 3), 256, 0, stream>>>(p);
    }
    // fs[:, m*128:(m+1)*128] = relu(f1 @ Wh2^T + bh2)
    {
        GemmP p{};
        for (int m = 0; m < 3; ++m) {
            p.A1[m] = f1 + m * NF; p.W1[m] = Wh2[m]; p.K1[m] = FD;
            p.b1[m] = bh2[m];      p.C[m] = fs + m * FD;
        }
        p.lda1 = FD; p.ldc = 3 * FD; p.relu = 1;
        gemm3_kernel<<<dim3(N_DIM / 64, FD / 64, 3), 256, 0, stream>>>(p);
    }
    // y
    y_kernel<<<(N_DIM * 64) / 256, 256, 0, stream>>>(fs, Wy, by, out_y);
}

// Round 11
// 1660.248 us; speedup vs baseline: 1.8128x; 1.8128x over previous
//
#include <hip/hip_runtime.h>

typedef __attribute__((ext_vector_type(8))) short short8;
typedef __attribute__((ext_vector_type(4))) float f32x4;
typedef unsigned short ushort_t;

#define T_DIM 64
#define N_DIM 4096
#define DL 300
#define DA 74
#define DV 35
#define DTOT 409
#define ZD 256
#define FD 128
#define KP1_L 320
#define KP1_A 96
#define KP1_V 64
#define KC_L ((KP1_L + 256) / 32)   // 18
#define KC_A ((KP1_A + 256) / 32)   // 11
#define KC_V ((KP1_V + 256) / 32)   // 10

__device__ __forceinline__ ushort_t f2bf(float v) {
    unsigned u = __float_as_uint(v);
    u += 0x7fffu + ((u >> 16) & 1u);
    return (ushort_t)(u >> 16);
}

__device__ __forceinline__ float fastrcp(float x) {
#if __has_builtin(__builtin_amdgcn_rcpf)
    return __builtin_amdgcn_rcpf(x);
#else
    return 1.f / x;
#endif
}

// async global->LDS, 16B per lane
__device__ __forceinline__ void async_lds16(const ushort_t* g, ushort_t* l) {
    __builtin_amdgcn_global_load_lds(
        (const __attribute__((address_space(1))) unsigned int*)g,
        (__attribute__((address_space(3))) unsigned int*)l, 16, 0, 0);
}

// ---------------------------------------------------------------------------
// prep: one pass over x -> (1) the three fp32 output slices, (2) bf16
// A-fragment buffers xf[m] : [t][nb][kc][lane][8].
// ---------------------------------------------------------------------------
struct PrepP {
    const float* x;
    float* ol;
    float* oa;
    float* ov;
    ushort_t* xf[3];
};
__global__ __launch_bounds__(256) void prep_kernel(PrepP p) {
    __shared__ float xrow[16][420];
    const int bid = blockIdx.x;
    const int t = bid >> 8, nb = bid & 255;
    const int tid = threadIdx.x;
    const size_t rowbase = (size_t)t * N_DIM + (size_t)nb * 16;

    const float* __restrict__ src = p.x + rowbase * DTOT;
    for (int e = tid; e < 16 * DTOT; e += 256) {
        int r = e / DTOT, d = e - r * DTOT;
        xrow[r][d] = src[e];
    }
    __syncthreads();

    {
        float* __restrict__ dl = p.ol + rowbase * DL;
        for (int e = tid; e < 16 * DL; e += 256) { int r = e / DL, d = e - r * DL; dl[e] = xrow[r][d]; }
        float* __restrict__ da = p.oa + rowbase * DA;
        for (int e = tid; e < 16 * DA; e += 256) { int r = e / DA, d = e - r * DA; da[e] = xrow[r][300 + d]; }
        float* __restrict__ dv = p.ov + rowbase * DV;
        for (int e = tid; e < 16 * DV; e += 256) { int r = e / DV, d = e - r * DV; dv[e] = xrow[r][374 + d]; }
    }

    const unsigned tnb = (unsigned)t * 256u + (unsigned)nb;
    for (int q = tid; q < 960; q += 256) {
        int m, kc, l, xkc, col0, dcap;
        if (q < 640)      { m = 0; kc = q >> 6;          l = q & 63; xkc = 10; col0 = 0;   dcap = DL; }
        else if (q < 832) { int qq = q - 640; m = 1; kc = qq >> 6; l = qq & 63; xkc = 3; col0 = 300; dcap = DA; }
        else              { int qq = q - 832; m = 2; kc = qq >> 6; l = qq & 63; xkc = 2; col0 = 374; dcap = DV; }
        int n16 = l & 15;
        int kb = kc * 32 + (l >> 4) * 8;
        ushort_t tmp[8];
#pragma unroll
        for (int j = 0; j < 8; ++j) {
            int k = kb + j;
            tmp[j] = (k < dcap) ? f2bf(xrow[n16][col0 + k]) : (ushort_t)0;
        }
        ushort_t* dst = p.xf[m] + (((size_t)tnb * xkc + kc) * 64 + l) * 8;
        *reinterpret_cast<short8*>(dst) = *reinterpret_cast<short8*>(tmp);
    }
}

// ---------------------------------------------------------------------------
// Weight conversion into B-fragment stream order:
// chunk id = ((zs*4 + g)*KC + kc), chunk = [lane 64][8] bf16.
// ---------------------------------------------------------------------------
struct WConvP {
    const float* Wih[3];
    const float* Whh[3];
    ushort_t* wf[3];
};
__global__ __launch_bounds__(256) void wconv_kernel(WConvP p) {
    const unsigned CL = 16u * 4 * KC_L * 64;
    const unsigned CA = 16u * 4 * KC_A * 64;
    const unsigned CV = 16u * 4 * KC_V * 64;
    unsigned e = blockIdx.x * 256u + threadIdx.x;
    int m, kcm, d, kp1;
    unsigned rel;
    if (e < CL)                { m = 0; rel = e;           kcm = KC_L; d = DL; kp1 = KP1_L; }
    else if (e < CL + CA)      { m = 1; rel = e - CL;      kcm = KC_A; d = DA; kp1 = KP1_A; }
    else if (e < CL + CA + CV) { m = 2; rel = e - CL - CA; kcm = KC_V; d = DV; kp1 = KP1_V; }
    else return;
    unsigned lane = rel & 63u;
    unsigned rest = rel >> 6;
    unsigned kc = rest % (unsigned)kcm;
    unsigned zg = rest / (unsigned)kcm;
    unsigned g = zg & 3u, zs = zg >> 2;
    unsigned row = g * 256u + zs * 16u + (lane & 15u);
    unsigned kb = kc * 32u + (lane >> 4) * 8u;
    const float* __restrict__ Wih = p.Wih[m];
    const float* __restrict__ Whh = p.Whh[m];
    ushort_t tmp[8];
#pragma unroll
    for (int j = 0; j < 8; ++j) {
        int k = (int)kb + j;
        float v = 0.f;
        if (k < d) v = Wih[(size_t)row * d + k];
        else if (k >= kp1) v = Whh[(size_t)row * 256u + (k - kp1)];
        tmp[j] = f2bf(v);
    }
    *reinterpret_cast<short8*>(p.wf[m] + (size_t)rel * 8) = *reinterpret_cast<short8*>(tmp);
}

// ---------------------------------------------------------------------------
// Independent-chain LSTM v4 (r9 geometry, 1024-thread blocks):
//  - 192 blocks x 1024 threads; block = (m, 64 rows); wave w owns zs slice w
//    (16 waves = 16 zs slices; the old pp pass-loop is now the wave dim)
//  - per-wave MFMA halves; 4 waves/SIMD doubles latency hiding
//  - identical memory streams to r9 (no L2 budget change): weights from L2
//    with 1-deep bcur/bnxt prefetch, x via async global_load_lds dbuf,
//    h in LDS dbuf, c in registers
// ---------------------------------------------------------------------------
struct ChainP {
    const ushort_t* xf[3];
    const ushort_t* wf[3];
    const float* bih[3];
    const float* bhh[3];
    float* hf;   // [3][N][256] f32, written at t=63
};

template <int KP1>
__device__ __forceinline__ void chain_body(const ChainP& p, int m, int row0, ushort_t* sh) {
    constexpr int XKC = KP1 / 32;
    constexpr int KC = XKC + 8;
    constexpr int XCH = 4 * XKC;            // x chunks per tile
    constexpr int XSZ = XCH * 512;          // ushorts per x buffer
    const int tid = threadIdx.x;
    const int w = tid >> 6;                 // 0..15 = zs slice
    const int lane = tid & 63, ln = lane & 15, lg = lane >> 4;
    const int nb0 = row0 >> 4;

    ushort_t* hb0 = sh;                     // 2 x 16384 ushorts (64 KB)
    ushort_t* xb0 = sh + 32768;             // 2 x XSZ
    const ushort_t* __restrict__ xf = p.xf[m];
    const ushort_t* __restrict__ wf = p.wf[m];

    // zero h buffer 0
    for (int e = tid; e < 8192; e += 1024) ((unsigned*)hb0)[e] = 0u;

    // prologue: async-stage x tile for t=0 into buffer 0
    for (int q = w; q < XCH; q += 16) {
        int rf = q / XKC, kc = q - rf * XKC;
        const ushort_t* src = xf + (((size_t)0 * 256 + nb0 + rf) * XKC + kc) * 512 + lane * 8;
        async_lds16(src, xb0 + (size_t)q * 512);
    }

    const int z = w * 16 + ln;
    float bb4[4];
#pragma unroll
    for (int g = 0; g < 4; ++g)
        bb4[g] = p.bih[m][g * 256 + z] + p.bhh[m][g * 256 + z];
    float creg[4][4] = {};
    asm volatile("s_waitcnt vmcnt(0)" ::: "memory");
    __syncthreads();

    const int kc2 = z >> 5;
    const int bofs = ((z >> 3) & 3) * 16;
    const int jj = z & 7;
    const ushort_t* __restrict__ wfz = wf + (size_t)w * 4 * KC * 512;

#pragma unroll 1
    for (int t = 0; t < T_DIM; ++t) {
        const ushort_t* __restrict__ xbc = xb0 + (size_t)(t & 1) * XSZ;
        const ushort_t* __restrict__ hbc = hb0 + (size_t)(t & 1) * 16384;
        ushort_t* __restrict__ hbn = hb0 + (size_t)((t & 1) ^ 1) * 16384;

        f32x4 acc[4][4] = {};
        short8 bcur[4];
#pragma unroll
        for (int g = 0; g < 4; ++g)
            bcur[g] = *reinterpret_cast<const short8*>(
                wfz + ((size_t)g * KC) * 512 + lane * 8);
#pragma unroll 1
        for (int kc = 0; kc < KC; ++kc) {
            short8 bnxt[4];
            if (kc + 1 < KC) {
#pragma unroll
                for (int g = 0; g < 4; ++g)
                    bnxt[g] = *reinterpret_cast<const short8*>(
                        wfz + ((size_t)g * KC + kc + 1) * 512 + lane * 8);
            }
            short8 a[4];
            if (kc < XKC) {
#pragma unroll
                for (int rf = 0; rf < 4; ++rf)
                    a[rf] = *reinterpret_cast<const short8*>(
                        xbc + ((size_t)(rf * XKC + kc) * 64 + lane) * 8);
            } else {
#pragma unroll
                for (int rf = 0; rf < 4; ++rf)
                    a[rf] = *reinterpret_cast<const short8*>(
                        hbc + ((size_t)(rf * 8 + (kc - XKC)) * 64 + lane) * 8);
            }
#pragma unroll
            for (int g = 0; g < 4; ++g)
#pragma unroll
                for (int rf = 0; rf < 4; ++rf)
                    acc[rf][g] = __builtin_amdgcn_mfma_f32_16x16x32_bf16(
                        a[rf], bcur[g], acc[rf][g], 0, 0, 0);
            if (kc + 1 < KC) {
#pragma unroll
                for (int g = 0; g < 4; ++g) bcur[g] = bnxt[g];
            }
        }

        // async-stage next step's x tile (covered by epilogue + barrier drain)
        if (t + 1 < T_DIM) {
            ushort_t* xbn = xb0 + (size_t)((t & 1) ^ 1) * XSZ;
            for (int q = w; q < XCH; q += 16) {
                int rf = q / XKC, kc = q - rf * XKC;
                const ushort_t* src =
                    xf + (((size_t)(t + 1) * 256 + nb0 + rf) * XKC + kc) * 512 + lane * 8;
                async_lds16(src, xbn + (size_t)q * 512);
            }
        }

        // pointwise epilogue; h -> LDS next buffer (A-frag layout)
#pragma unroll
        for (int rf = 0; rf < 4; ++rf) {
#pragma unroll
            for (int reg = 0; reg < 4; ++reg) {
                float gi = acc[rf][0][reg] + bb4[0];
                float gf = acc[rf][1][reg] + bb4[1];
                float gg = acc[rf][2][reg] + bb4[2];
                float go = acc[rf][3][reg] + bb4[3];
                float i_ = fastrcp(1.f + __expf(-gi));
                float f_ = fastrcp(1.f + __expf(-gf));
                float g_ = 1.f - 2.f * fastrcp(1.f + __expf(2.f * gg));
                float o_ = fastrcp(1.f + __expf(-go));
                float cc = f_ * creg[rf][reg] + i_ * g_;
                creg[rf][reg] = cc;
                float hh = o_ * (1.f - 2.f * fastrcp(1.f + __expf(2.f * cc)));
                hbn[((size_t)(rf * 8 + kc2) * 64 + (lg * 4 + reg + bofs)) * 8 + jj] = f2bf(hh);
                if (t == T_DIM - 1) {
                    int nl = rf * 16 + lg * 4 + reg;
                    p.hf[(size_t)m * N_DIM * ZD + (size_t)(row0 + nl) * ZD + z] = hh;
                }
            }
        }

        // drain next-step x-tile loads, then step barrier
        asm volatile("s_waitcnt vmcnt(0)" ::: "memory");
        __syncthreads();
    }
}

__global__ __launch_bounds__(1024, 1) void lstm_chain_kernel(ChainP p) {
    __shared__ ushort_t sh[73728];   // 64 KB h-dbuf + up to 80 KB x-dbuf
    const int bid = blockIdx.x;
    const int r8 = bid & 7, idx = bid >> 3;
    const int m = idx >> 3;
    const int bm = (idx & 7) * 8 + r8;        // 0..63
    const int row0 = bm * 64;
    if (m == 0)      chain_body<KP1_L>(p, 0, row0, sh);
    else if (m == 1) chain_body<KP1_A>(p, 1, row0, sh);
    else             chain_body<KP1_V>(p, 2, row0, sh);
}

// ---------------------------------------------------------------------------
// fp32 tiled GEMM for the head layers
// ---------------------------------------------------------------------------
struct GemmP {
    const float* A1[3];
    const float* W1[3];
    const float* b1[3];
    float* C[3];
    int K1[3];
    int lda1;
    int ldc;
    int relu;
};

__device__ __forceinline__ void mac16(const float (&As)[16][64], const float (&Ws)[16][64],
                                      int tx, int ty, float (&acc)[4][4]) {
#pragma unroll
    for (int k = 0; k < 16; ++k) {
        float4 av = *reinterpret_cast<const float4*>(&As[k][ty * 4]);
        float4 bv = *reinterpret_cast<const float4*>(&Ws[k][tx * 4]);
        float a[4] = {av.x, av.y, av.z, av.w};
        float b[4] = {bv.x, bv.y, bv.z, bv.w};
#pragma unroll
        for (int i = 0; i < 4; ++i)
#pragma unroll
            for (int j = 0; j < 4; ++j)
                acc[i][j] = fmaf(a[i], b[j], acc[i][j]);
    }
}

__global__ __launch_bounds__(256) void gemm3_kernel(GemmP p) {
    const int m = blockIdx.z;
    const float* __restrict__ A1 = p.A1[m];
    const float* __restrict__ W1 = p.W1[m];
    const int K1 = p.K1[m];
    float* __restrict__ C = p.C[m];
    const int row0 = blockIdx.x * 64;
    const int col0 = blockIdx.y * 64;

    __shared__ __align__(16) float As[16][64];
    __shared__ __align__(16) float Ws[16][64];

    const int tid = threadIdx.x;
    const int tx = tid & 15, ty = tid >> 4;
    float acc[4][4] = {};

    for (int k0 = 0; k0 < K1; k0 += 16) {
#pragma unroll
        for (int i = 0; i < 4; ++i) {
            int e = tid * 4 + i;
            int rr = e >> 4, k = e & 15;
            int kk = k0 + k;
            As[k][rr] = (kk < K1) ? A1[(size_t)(row0 + rr) * p.lda1 + kk] : 0.f;
            Ws[k][rr] = (kk < K1) ? W1[(size_t)(col0 + rr) * K1 + kk] : 0.f;
        }
        __syncthreads();
        mac16(As, Ws, tx, ty, acc);
        __syncthreads();
    }

    const float* __restrict__ b1 = p.b1[m];
#pragma unroll
    for (int i = 0; i < 4; ++i) {
        int rr = row0 + ty * 4 + i;
        float v[4];
#pragma unroll
        for (int j = 0; j < 4; ++j) {
            int cc = col0 + tx * 4 + j;
            float tvl = acc[i][j] + b1[cc];
            if (p.relu) tvl = fmaxf(tvl, 0.f);
            v[j] = tvl;
        }
        float4 o = make_float4(v[0], v[1], v[2], v[3]);
        *reinterpret_cast<float4*>(&C[(size_t)rr * p.ldc + col0 + tx * 4]) = o;
    }
}

// ---------------------------------------------------------------------------
// y[n] = dot(fs[n,:384], Wy) + by
// ---------------------------------------------------------------------------
__global__ __launch_bounds__(256) void y_kernel(const float* __restrict__ fs,
                                                const float* __restrict__ Wy,
                                                const float* __restrict__ by,
                                                float* __restrict__ y) {
    unsigned wave = (blockIdx.x * 256u + threadIdx.x) >> 6;
    unsigned lane = threadIdx.x & 63u;
    if (wave >= N_DIM) return;
    const float* row = fs + (size_t)wave * 3 * FD;
    float s = 0.f;
    for (unsigned j = lane; j < 3 * FD; j += 64) s += row[j] * Wy[j];
#pragma unroll
    for (int off = 32; off; off >>= 1) s += __shfl_down(s, off);
    if (lane == 0) y[wave] = s + by[0];
}

extern "C" void kernel_launch(void* const* d_in, const int* in_sizes, int n_in,
                              void* d_out, int out_size, void* d_ws, size_t ws_size,
                              hipStream_t stream) {
    const float* x = (const float*)d_in[0];
    const float *W_ih[3], *W_hh[3], *b_ih[3], *b_hh[3], *Wfc[3], *bfc[3],
                *Wh1[3], *bh1[3], *Wh2[3], *bh2[3];
    for (int m = 0; m < 3; ++m) {
        const int b = 1 + m * 10;
        W_ih[m] = (const float*)d_in[b + 0];
        W_hh[m] = (const float*)d_in[b + 1];
        b_ih[m] = (const float*)d_in[b + 2];
        b_hh[m] = (const float*)d_in[b + 3];
        Wfc[m]  = (const float*)d_in[b + 4];
        bfc[m]  = (const float*)d_in[b + 5];
        Wh1[m]  = (const float*)d_in[b + 6];
        bh1[m]  = (const float*)d_in[b + 7];
        Wh2[m]  = (const float*)d_in[b + 8];
        bh2[m]  = (const float*)d_in[b + 9];
    }
    const float* Wy = (const float*)d_in[31];
    const float* by = (const float*)d_in[32];

    float* out   = (float*)d_out;
    float* out_l = out;
    float* out_a = out_l + (size_t)T_DIM * N_DIM * DL;
    float* out_v = out_a + (size_t)T_DIM * N_DIM * DA;
    float* out_y = out_v + (size_t)T_DIM * N_DIM * DV;

    const size_t NZ = (size_t)N_DIM * ZD;
    const size_t NF = (size_t)N_DIM * FD;
    const size_t WFL = (size_t)16 * 4 * KC_L * 512;
    const size_t WFA = (size_t)16 * 4 * KC_A * 512;
    const size_t WFV = (size_t)16 * 4 * KC_V * 512;

    // workspace layout
    char* wsb = (char*)d_ws;
    float* hf   = (float*)wsb;                              // 3NZ f32
    float* zbuf = hf + 3 * NZ;
    float* f1   = zbuf + 3 * NZ;
    float* fs   = f1 + 3 * NF;
    ushort_t* wf_l = (ushort_t*)(fs + 3 * NF);
    ushort_t* wf_a = wf_l + WFL;
    ushort_t* wf_v = wf_a + WFA;
    ushort_t* xf_l = wf_v + WFV;                            // T*N*320
    ushort_t* xf_a = xf_l + (size_t)T_DIM * N_DIM * KP1_L;  // T*N*96
    ushort_t* xf_v = xf_a + (size_t)T_DIM * N_DIM * KP1_A;  // T*N*64
    size_t need = (size_t)((char*)(xf_v + (size_t)T_DIM * N_DIM * KP1_V) - wsb);
    if (ws_size < need) return;

    // weight fragment conversion
    {
        WConvP p{};
        for (int m = 0; m < 3; ++m) { p.Wih[m] = W_ih[m]; p.Whh[m] = W_hh[m]; }
        p.wf[0] = wf_l; p.wf[1] = wf_a; p.wf[2] = wf_v;
        wconv_kernel<<<(16 * 4 * (KC_L + KC_A + KC_V) * 64) / 256, 256, 0, stream>>>(p);
    }

    // fused split + x fragment conversion
    {
        PrepP p{};
        p.x = x;
        p.ol = out_l; p.oa = out_a; p.ov = out_v;
        p.xf[0] = xf_l; p.xf[1] = xf_a; p.xf[2] = xf_v;
        prep_kernel<<<T_DIM * 256, 256, 0, stream>>>(p);
    }

    // independent-chain LSTM (192 blocks x 1024 threads)
    {
        ChainP cp{};
        cp.xf[0] = xf_l; cp.xf[1] = xf_a; cp.xf[2] = xf_v;
        cp.wf[0] = wf_l; cp.wf[1] = wf_a; cp.wf[2] = wf_v;
        for (int m = 0; m < 3; ++m) { cp.bih[m] = b_ih[m]; cp.bhh[m] = b_hh[m]; }
        cp.hf = hf;
        lstm_chain_kernel<<<192, 1024, 0, stream>>>(cp);
    }

    // z = h @ Wfc^T + bfc
    {
        GemmP p{};
        for (int m = 0; m < 3; ++m) {
            p.A1[m] = hf + m * NZ; p.W1[m] = Wfc[m]; p.K1[m] = ZD;
            p.b1[m] = bfc[m];      p.C[m] = zbuf + m * NZ;
        }
        p.lda1 = ZD; p.ldc = ZD; p.relu = 0;
        gemm3_kernel<<<dim3(N_DIM / 64, ZD / 64, 3), 256, 0, stream>>>(p);
    }
    // f1 = relu(z @ Wh1^T + bh1)
    {
        GemmP p{};
        for (int m = 0; m < 3; ++m) {
            p.A1[m] = zbuf + m * NZ; p.W1[m] = Wh1[m]; p.K1[m] = ZD;
            p.b1[m] = bh1[m];        p.C[m] = f1 + m * NF;
        }
        p.lda1 = ZD; p.ldc = FD; p.relu = 1;
        gemm3_kernel<<<dim3(N_DIM / 64, FD / 64, 3), 256, 0, stream>>>(p);
    }
    // fs[:, m*128:(m+1)*128] = relu(f1 @ Wh2^T + bh2)
    {
        GemmP p{};
        for (int m = 0; m < 3; ++m) {
            p.A1[m] = f1 + m * NF; p.W1[m] = Wh2[m]; p.K1[m] = FD;
            p.b1[m] = bh2[m];      p.C[m] = fs + m * FD;
        }
        p.lda1 = FD; p.ldc = 3 * FD; p.relu = 1;
        gemm3_kernel<<<dim3(N_DIM / 64, FD / 64, 3), 256, 0, stream>>>(p);
    }
    // y
    y_kernel<<<(N_DIM * 64) / 256, 256, 0, stream>>>(fs, Wy, by, out_y);
}

// Round 12
// 1257.063 us; speedup vs baseline: 2.3943x; 1.3207x over previous
//
#include <hip/hip_runtime.h>

typedef __attribute__((ext_vector_type(8))) short short8;
typedef __attribute__((ext_vector_type(4))) float f32x4;
typedef unsigned short ushort_t;

#define T_DIM 64
#define N_DIM 4096
#define DL 300
#define DA 74
#define DV 35
#define DTOT 409
#define ZD 256
#define FD 128
#define KP1_L 320
#define KP1_A 96
#define KP1_V 64
#define KC_L ((KP1_L + 256) / 32)   // 18
#define KC_A ((KP1_A + 256) / 32)   // 11
#define KC_V ((KP1_V + 256) / 32)   // 10

__device__ __forceinline__ ushort_t f2bf(float v) {
    unsigned u = __float_as_uint(v);
    u += 0x7fffu + ((u >> 16) & 1u);
    return (ushort_t)(u >> 16);
}

__device__ __forceinline__ float fastrcp(float x) {
#if __has_builtin(__builtin_amdgcn_rcpf)
    return __builtin_amdgcn_rcpf(x);
#else
    return 1.f / x;
#endif
}

// async global->LDS, 16B per lane
__device__ __forceinline__ void async_lds16(const ushort_t* g, ushort_t* l) {
    __builtin_amdgcn_global_load_lds(
        (const __attribute__((address_space(1))) unsigned int*)g,
        (__attribute__((address_space(3))) unsigned int*)l, 16, 0, 0);
}

// ---------------------------------------------------------------------------
// prep: one pass over x -> (1) the three fp32 output slices, (2) bf16
// A-fragment buffers xf[m] : [t][nb][kc][lane][8].
// ---------------------------------------------------------------------------
struct PrepP {
    const float* x;
    float* ol;
    float* oa;
    float* ov;
    ushort_t* xf[3];
};
__global__ __launch_bounds__(256) void prep_kernel(PrepP p) {
    __shared__ float xrow[16][420];
    const int bid = blockIdx.x;
    const int t = bid >> 8, nb = bid & 255;
    const int tid = threadIdx.x;
    const size_t rowbase = (size_t)t * N_DIM + (size_t)nb * 16;

    const float* __restrict__ src = p.x + rowbase * DTOT;
    for (int e = tid; e < 16 * DTOT; e += 256) {
        int r = e / DTOT, d = e - r * DTOT;
        xrow[r][d] = src[e];
    }
    __syncthreads();

    {
        float* __restrict__ dl = p.ol + rowbase * DL;
        for (int e = tid; e < 16 * DL; e += 256) { int r = e / DL, d = e - r * DL; dl[e] = xrow[r][d]; }
        float* __restrict__ da = p.oa + rowbase * DA;
        for (int e = tid; e < 16 * DA; e += 256) { int r = e / DA, d = e - r * DA; da[e] = xrow[r][300 + d]; }
        float* __restrict__ dv = p.ov + rowbase * DV;
        for (int e = tid; e < 16 * DV; e += 256) { int r = e / DV, d = e - r * DV; dv[e] = xrow[r][374 + d]; }
    }

    const unsigned tnb = (unsigned)t * 256u + (unsigned)nb;
    for (int q = tid; q < 960; q += 256) {
        int m, kc, l, xkc, col0, dcap;
        if (q < 640)      { m = 0; kc = q >> 6;          l = q & 63; xkc = 10; col0 = 0;   dcap = DL; }
        else if (q < 832) { int qq = q - 640; m = 1; kc = qq >> 6; l = qq & 63; xkc = 3; col0 = 300; dcap = DA; }
        else              { int qq = q - 832; m = 2; kc = qq >> 6; l = qq & 63; xkc = 2; col0 = 374; dcap = DV; }
        int n16 = l & 15;
        int kb = kc * 32 + (l >> 4) * 8;
        ushort_t tmp[8];
#pragma unroll
        for (int j = 0; j < 8; ++j) {
            int k = kb + j;
            tmp[j] = (k < dcap) ? f2bf(xrow[n16][col0 + k]) : (ushort_t)0;
        }
        ushort_t* dst = p.xf[m] + (((size_t)tnb * xkc + kc) * 64 + l) * 8;
        *reinterpret_cast<short8*>(dst) = *reinterpret_cast<short8*>(tmp);
    }
}

// ---------------------------------------------------------------------------
// Weight conversion into B-fragment stream order:
// chunk id = ((zs*4 + g)*KC + kc), chunk = [lane 64][8] bf16.
// ---------------------------------------------------------------------------
struct WConvP {
    const float* Wih[3];
    const float* Whh[3];
    ushort_t* wf[3];
};
__global__ __launch_bounds__(256) void wconv_kernel(WConvP p) {
    const unsigned CL = 16u * 4 * KC_L * 64;
    const unsigned CA = 16u * 4 * KC_A * 64;
    const unsigned CV = 16u * 4 * KC_V * 64;
    unsigned e = blockIdx.x * 256u + threadIdx.x;
    int m, kcm, d, kp1;
    unsigned rel;
    if (e < CL)                { m = 0; rel = e;           kcm = KC_L; d = DL; kp1 = KP1_L; }
    else if (e < CL + CA)      { m = 1; rel = e - CL;      kcm = KC_A; d = DA; kp1 = KP1_A; }
    else if (e < CL + CA + CV) { m = 2; rel = e - CL - CA; kcm = KC_V; d = DV; kp1 = KP1_V; }
    else return;
    unsigned lane = rel & 63u;
    unsigned rest = rel >> 6;
    unsigned kc = rest % (unsigned)kcm;
    unsigned zg = rest / (unsigned)kcm;
    unsigned g = zg & 3u, zs = zg >> 2;
    unsigned row = g * 256u + zs * 16u + (lane & 15u);
    unsigned kb = kc * 32u + (lane >> 4) * 8u;
    const float* __restrict__ Wih = p.Wih[m];
    const float* __restrict__ Whh = p.Whh[m];
    ushort_t tmp[8];
#pragma unroll
    for (int j = 0; j < 8; ++j) {
        int k = (int)kb + j;
        float v = 0.f;
        if (k < d) v = Wih[(size_t)row * d + k];
        else if (k >= kp1) v = Whh[(size_t)row * 256u + (k - kp1)];
        tmp[j] = f2bf(v);
    }
    *reinterpret_cast<short8*>(p.wf[m] + (size_t)rel * 8) = *reinterpret_cast<short8*>(tmp);
}

// ---------------------------------------------------------------------------
// Independent-chain LSTM v5 (r11 geometry, register-budget pinned):
//  - 192 blocks x 1024 threads; block = (m, 64 rows); wave w owns zs slice w
//  - amdgpu_waves_per_eu(4,4): exactly 4 waves/EU (LDS forces 1 block/CU
//    anyway) -> compiler gets the full 128-VGPR budget, no spill squeeze
//  - NO b software prefetch (fits 128 VGPR); latency hidden by 4-wave TLP
//  - x via async global_load_lds double buffer; h in LDS dbuf; c in regs
// ---------------------------------------------------------------------------
struct ChainP {
    const ushort_t* xf[3];
    const ushort_t* wf[3];
    const float* bih[3];
    const float* bhh[3];
    float* hf;   // [3][N][256] f32, written at t=63
};

template <int KP1>
__device__ __forceinline__ void chain_body(const ChainP& p, int m, int row0, ushort_t* sh) {
    constexpr int XKC = KP1 / 32;
    constexpr int KC = XKC + 8;
    constexpr int XCH = 4 * XKC;            // x chunks per tile
    constexpr int XSZ = XCH * 512;          // ushorts per x buffer
    const int tid = threadIdx.x;
    const int w = tid >> 6;                 // 0..15 = zs slice
    const int lane = tid & 63, ln = lane & 15, lg = lane >> 4;
    const int nb0 = row0 >> 4;

    ushort_t* hb0 = sh;                     // 2 x 16384 ushorts (64 KB)
    ushort_t* xb0 = sh + 32768;             // 2 x XSZ
    const ushort_t* __restrict__ xf = p.xf[m];
    const ushort_t* __restrict__ wf = p.wf[m];

    // zero h buffer 0
    for (int e = tid; e < 8192; e += 1024) ((unsigned*)hb0)[e] = 0u;

    // prologue: async-stage x tile for t=0 into buffer 0
    for (int q = w; q < XCH; q += 16) {
        int rf = q / XKC, kc = q - rf * XKC;
        const ushort_t* src = xf + (((size_t)0 * 256 + nb0 + rf) * XKC + kc) * 512 + lane * 8;
        async_lds16(src, xb0 + (size_t)q * 512);
    }

    const int z = w * 16 + ln;
    float bb4[4];
#pragma unroll
    for (int g = 0; g < 4; ++g)
        bb4[g] = p.bih[m][g * 256 + z] + p.bhh[m][g * 256 + z];
    float creg[4][4] = {};
    asm volatile("s_waitcnt vmcnt(0)" ::: "memory");
    __syncthreads();

    const int kc2 = z >> 5;
    const int bofs = ((z >> 3) & 3) * 16;
    const int jj = z & 7;
    const ushort_t* __restrict__ wfz = wf + (size_t)w * 4 * KC * 512;

#pragma unroll 1
    for (int t = 0; t < T_DIM; ++t) {
        const ushort_t* __restrict__ xbc = xb0 + (size_t)(t & 1) * XSZ;
        const ushort_t* __restrict__ hbc = hb0 + (size_t)(t & 1) * 16384;
        ushort_t* __restrict__ hbn = hb0 + (size_t)((t & 1) ^ 1) * 16384;

        f32x4 acc[4][4] = {};
#pragma unroll 1
        for (int kc = 0; kc < KC; ++kc) {
            short8 b[4];
#pragma unroll
            for (int g = 0; g < 4; ++g)
                b[g] = *reinterpret_cast<const short8*>(
                    wfz + ((size_t)g * KC + kc) * 512 + lane * 8);
            short8 a[4];
            if (kc < XKC) {
#pragma unroll
                for (int rf = 0; rf < 4; ++rf)
                    a[rf] = *reinterpret_cast<const short8*>(
                        xbc + ((size_t)(rf * XKC + kc) * 64 + lane) * 8);
            } else {
#pragma unroll
                for (int rf = 0; rf < 4; ++rf)
                    a[rf] = *reinterpret_cast<const short8*>(
                        hbc + ((size_t)(rf * 8 + (kc - XKC)) * 64 + lane) * 8);
            }
#pragma unroll
            for (int g = 0; g < 4; ++g)
#pragma unroll
                for (int rf = 0; rf < 4; ++rf)
                    acc[rf][g] = __builtin_amdgcn_mfma_f32_16x16x32_bf16(
                        a[rf], b[g], acc[rf][g], 0, 0, 0);
        }

        // async-stage next step's x tile (covered by epilogue + barrier drain)
        if (t + 1 < T_DIM) {
            ushort_t* xbn = xb0 + (size_t)((t & 1) ^ 1) * XSZ;
            for (int q = w; q < XCH; q += 16) {
                int rf = q / XKC, kc = q - rf * XKC;
                const ushort_t* src =
                    xf + (((size_t)(t + 1) * 256 + nb0 + rf) * XKC + kc) * 512 + lane * 8;
                async_lds16(src, xbn + (size_t)q * 512);
            }
        }

        // pointwise epilogue; h -> LDS next buffer (A-frag layout)
#pragma unroll
        for (int rf = 0; rf < 4; ++rf) {
#pragma unroll
            for (int reg = 0; reg < 4; ++reg) {
                float gi = acc[rf][0][reg] + bb4[0];
                float gf = acc[rf][1][reg] + bb4[1];
                float gg = acc[rf][2][reg] + bb4[2];
                float go = acc[rf][3][reg] + bb4[3];
                float i_ = fastrcp(1.f + __expf(-gi));
                float f_ = fastrcp(1.f + __expf(-gf));
                float g_ = 1.f - 2.f * fastrcp(1.f + __expf(2.f * gg));
                float o_ = fastrcp(1.f + __expf(-go));
                float cc = f_ * creg[rf][reg] + i_ * g_;
                creg[rf][reg] = cc;
                float hh = o_ * (1.f - 2.f * fastrcp(1.f + __expf(2.f * cc)));
                hbn[((size_t)(rf * 8 + kc2) * 64 + (lg * 4 + reg + bofs)) * 8 + jj] = f2bf(hh);
                if (t == T_DIM - 1) {
                    int nl = rf * 16 + lg * 4 + reg;
                    p.hf[(size_t)m * N_DIM * ZD + (size_t)(row0 + nl) * ZD + z] = hh;
                }
            }
        }

        // drain next-step x-tile loads, then step barrier
        asm volatile("s_waitcnt vmcnt(0)" ::: "memory");
        __syncthreads();
    }
}

__global__ __launch_bounds__(1024)
__attribute__((amdgpu_waves_per_eu(4, 4)))
void lstm_chain_kernel(ChainP p) {
    __shared__ ushort_t sh[73728];   // 64 KB h-dbuf + up to 80 KB x-dbuf
    const int bid = blockIdx.x;
    const int r8 = bid & 7, idx = bid >> 3;
    const int m = idx >> 3;
    const int bm = (idx & 7) * 8 + r8;        // 0..63
    const int row0 = bm * 64;
    if (m == 0)      chain_body<KP1_L>(p, 0, row0, sh);
    else if (m == 1) chain_body<KP1_A>(p, 1, row0, sh);
    else             chain_body<KP1_V>(p, 2, row0, sh);
}

// ---------------------------------------------------------------------------
// fp32 tiled GEMM for the head layers
// ---------------------------------------------------------------------------
struct GemmP {
    const float* A1[3];
    const float* W1[3];
    const float* b1[3];
    float* C[3];
    int K1[3];
    int lda1;
    int ldc;
    int relu;
};

__device__ __forceinline__ void mac16(const float (&As)[16][64], const float (&Ws)[16][64],
                                      int tx, int ty, float (&acc)[4][4]) {
#pragma unroll
    for (int k = 0; k < 16; ++k) {
        float4 av = *reinterpret_cast<const float4*>(&As[k][ty * 4]);
        float4 bv = *reinterpret_cast<const float4*>(&Ws[k][tx * 4]);
        float a[4] = {av.x, av.y, av.z, av.w};
        float b[4] = {bv.x, bv.y, bv.z, bv.w};
#pragma unroll
        for (int i = 0; i < 4; ++i)
#pragma unroll
            for (int j = 0; j < 4; ++j)
                acc[i][j] = fmaf(a[i], b[j], acc[i][j]);
    }
}

__global__ __launch_bounds__(256) void gemm3_kernel(GemmP p) {
    const int m = blockIdx.z;
    const float* __restrict__ A1 = p.A1[m];
    const float* __restrict__ W1 = p.W1[m];
    const int K1 = p.K1[m];
    float* __restrict__ C = p.C[m];
    const int row0 = blockIdx.x * 64;
    const int col0 = blockIdx.y * 64;

    __shared__ __align__(16) float As[16][64];
    __shared__ __align__(16) float Ws[16][64];

    const int tid = threadIdx.x;
    const int tx = tid & 15, ty = tid >> 4;
    float acc[4][4] = {};

    for (int k0 = 0; k0 < K1; k0 += 16) {
#pragma unroll
        for (int i = 0; i < 4; ++i) {
            int e = tid * 4 + i;
            int rr = e >> 4, k = e & 15;
            int kk = k0 + k;
            As[k][rr] = (kk < K1) ? A1[(size_t)(row0 + rr) * p.lda1 + kk] : 0.f;
            Ws[k][rr] = (kk < K1) ? W1[(size_t)(col0 + rr) * K1 + kk] : 0.f;
        }
        __syncthreads();
        mac16(As, Ws, tx, ty, acc);
        __syncthreads();
    }

    const float* __restrict__ b1 = p.b1[m];
#pragma unroll
    for (int i = 0; i < 4; ++i) {
        int rr = row0 + ty * 4 + i;
        float v[4];
#pragma unroll
        for (int j = 0; j < 4; ++j) {
            int cc = col0 + tx * 4 + j;
            float tvl = acc[i][j] + b1[cc];
            if (p.relu) tvl = fmaxf(tvl, 0.f);
            v[j] = tvl;
        }
        float4 o = make_float4(v[0], v[1], v[2], v[3]);
        *reinterpret_cast<float4*>(&C[(size_t)rr * p.ldc + col0 + tx * 4]) = o;
    }
}

// ---------------------------------------------------------------------------
// y[n] = dot(fs[n,:384], Wy) + by
// ---------------------------------------------------------------------------
__global__ __launch_bounds__(256) void y_kernel(const float* __restrict__ fs,
                                                const float* __restrict__ Wy,
                                                const float* __restrict__ by,
                                                float* __restrict__ y) {
    unsigned wave = (blockIdx.x * 256u + threadIdx.x) >> 6;
    unsigned lane = threadIdx.x & 63u;
    if (wave >= N_DIM) return;
    const float* row = fs + (size_t)wave * 3 * FD;
    float s = 0.f;
    for (unsigned j = lane; j < 3 * FD; j += 64) s += row[j] * Wy[j];
#pragma unroll
    for (int off = 32; off; off >>= 1) s += __shfl_down(s, off);
    if (lane == 0) y[wave] = s + by[0];
}

extern "C" void kernel_launch(void* const* d_in, const int* in_sizes, int n_in,
                              void* d_out, int out_size, void* d_ws, size_t ws_size,
                              hipStream_t stream) {
    const float* x = (const float*)d_in[0];
    const float *W_ih[3], *W_hh[3], *b_ih[3], *b_hh[3], *Wfc[3], *bfc[3],
                *Wh1[3], *bh1[3], *Wh2[3], *bh2[3];
    for (int m = 0; m < 3; ++m) {
        const int b = 1 + m * 10;
        W_ih[m] = (const float*)d_in[b + 0];
        W_hh[m] = (const float*)d_in[b + 1];
        b_ih[m] = (const float*)d_in[b + 2];
        b_hh[m] = (const float*)d_in[b + 3];
        Wfc[m]  = (const float*)d_in[b + 4];
        bfc[m]  = (const float*)d_in[b + 5];
        Wh1[m]  = (const float*)d_in[b + 6];
        bh1[m]  = (const float*)d_in[b + 7];
        Wh2[m]  = (const float*)d_in[b + 8];
        bh2[m]  = (const float*)d_in[b + 9];
    }
    const float* Wy = (const float*)d_in[31];
    const float* by = (const float*)d_in[32];

    float* out   = (float*)d_out;
    float* out_l = out;
    float* out_a = out_l + (size_t)T_DIM * N_DIM * DL;
    float* out_v = out_a + (size_t)T_DIM * N_DIM * DA;
    float* out_y = out_v + (size_t)T_DIM * N_DIM * DV;

    const size_t NZ = (size_t)N_DIM * ZD;
    const size_t NF = (size_t)N_DIM * FD;
    const size_t WFL = (size_t)16 * 4 * KC_L * 512;
    const size_t WFA = (size_t)16 * 4 * KC_A * 512;
    const size_t WFV = (size_t)16 * 4 * KC_V * 512;

    // workspace layout
    char* wsb = (char*)d_ws;
    float* hf   = (float*)wsb;                              // 3NZ f32
    float* zbuf = hf + 3 * NZ;
    float* f1   = zbuf + 3 * NZ;
    float* fs   = f1 + 3 * NF;
    ushort_t* wf_l = (ushort_t*)(fs + 3 * NF);
    ushort_t* wf_a = wf_l + WFL;
    ushort_t* wf_v = wf_a + WFA;
    ushort_t* xf_l = wf_v + WFV;                            // T*N*320
    ushort_t* xf_a = xf_l + (size_t)T_DIM * N_DIM * KP1_L;  // T*N*96
    ushort_t* xf_v = xf_a + (size_t)T_DIM * N_DIM * KP1_A;  // T*N*64
    size_t need = (size_t)((char*)(xf_v + (size_t)T_DIM * N_DIM * KP1_V) - wsb);
    if (ws_size < need) return;

    // weight fragment conversion
    {
        WConvP p{};
        for (int m = 0; m < 3; ++m) { p.Wih[m] = W_ih[m]; p.Whh[m] = W_hh[m]; }
        p.wf[0] = wf_l; p.wf[1] = wf_a; p.wf[2] = wf_v;
        wconv_kernel<<<(16 * 4 * (KC_L + KC_A + KC_V) * 64) / 256, 256, 0, stream>>>(p);
    }

    // fused split + x fragment conversion
    {
        PrepP p{};
        p.x = x;
        p.ol = out_l; p.oa = out_a; p.ov = out_v;
        p.xf[0] = xf_l; p.xf[1] = xf_a; p.xf[2] = xf_v;
        prep_kernel<<<T_DIM * 256, 256, 0, stream>>>(p);
    }

    // independent-chain LSTM (192 blocks x 1024 threads)
    {
        ChainP cp{};
        cp.xf[0] = xf_l; cp.xf[1] = xf_a; cp.xf[2] = xf_v;
        cp.wf[0] = wf_l; cp.wf[1] = wf_a; cp.wf[2] = wf_v;
        for (int m = 0; m < 3; ++m) { cp.bih[m] = b_ih[m]; cp.bhh[m] = b_hh[m]; }
        cp.hf = hf;
        lstm_chain_kernel<<<192, 1024, 0, stream>>>(cp);
    }

    // z = h @ Wfc^T + bfc
    {
        GemmP p{};
        for (int m = 0; m < 3; ++m) {
            p.A1[m] = hf + m * NZ; p.W1[m] = Wfc[m]; p.K1[m] = ZD;
            p.b1[m] = bfc[m];      p.C[m] = zbuf + m * NZ;
        }
        p.lda1 = ZD; p.ldc = ZD; p.relu = 0;
        gemm3_kernel<<<dim3(N_DIM / 64, ZD / 64, 3), 256, 0, stream>>>(p);
    }
    // f1 = relu(z @ Wh1^T + bh1)
    {
        GemmP p{};
        for (int m = 0; m < 3; ++m) {
            p.A1[m] = zbuf + m * NZ; p.W1[m] = Wh1[m]; p.K1[m] = ZD;
            p.b1[m] = bh1[m];        p.C[m] = f1 + m * NF;
        }
        p.lda1 = ZD; p.ldc = FD; p.relu = 1;
        gemm3_kernel<<<dim3(N_DIM / 64, FD / 64, 3), 256, 0, stream>>>(p);
    }
    // fs[:, m*128:(m+1)*128] = relu(f1 @ Wh2^T + bh2)
    {
        GemmP p{};
        for (int m = 0; m < 3; ++m) {
            p.A1[m] = f1 + m * NF; p.W1[m] = Wh2[m]; p.K1[m] = FD;
            p.b1[m] = bh2[m];      p.C[m] = fs + m * FD;
        }
        p.lda1 = FD; p.ldc = 3 * FD; p.relu = 1;
        gemm3_kernel<<<dim3(N_DIM / 64, FD / 64, 3), 256, 0, stream>>>(p);
    }
    // y
    y_kernel<<<(N_DIM * 64) / 256, 256, 0, stream>>>(fs, Wy, by, out_y);
}